// Round 3
// baseline (184.824 us; speedup 1.0000x reference)
//
#include <hip/hip_runtime.h>
#include <math.h>

#define EMB_DIM 512
#define N_Q 8
#define GAMMA_F 12.0f

typedef float f32x4 __attribute__((ext_vector_type(4)));

// ---------------------------------------------------------------------------
// Pre-kernel: rotate the 8 queries once, write to workspace.
//   ws[0      .. 4096)  = re_e  (8 queries x 512 dims)
//   ws[4096   .. 8192)  = im_e
// ---------------------------------------------------------------------------
__global__ __launch_bounds__(256) void rotate_queries_kernel(
    const int* __restrict__ all_h,
    const int* __restrict__ all_r,
    const float* __restrict__ eemb,
    const float* __restrict__ remb,
    float* __restrict__ ws)
{
    const int p = blockIdx.x * 256 + threadIdx.x;   // p = b*512 + j, p < 4096
    const int b = p >> 9;
    const int j = p & (EMB_DIM - 1);
    const int h = all_h[b];
    const int r = all_r[b];
    const float SCALE = (float)(M_PI * (double)EMB_DIM / 14.0);
    float re_h = eemb[(size_t)h * (2 * EMB_DIM) + j];
    float im_h = eemb[(size_t)h * (2 * EMB_DIM) + EMB_DIM + j];
    float phase = remb[r * EMB_DIM + j] * SCALE;
    float s, c;
    __sincosf(phase, &s, &c);
    ws[p]                 = re_h * c - im_h * s;
    ws[N_Q * EMB_DIM + p] = re_h * s + im_h * c;
}

// ---------------------------------------------------------------------------
// Scorer: wave-owns-entity, queries in registers, intra-wave reduction.
//
// Lane l holds dims {4l..4l+3} and {256+4l..+3} of all 8 rotated queries
// (128 VGPRs, loaded once). Per entity: 4x coalesced 1KB dwordx4 loads
// (every 64B line touched exactly once -> minimal L1 tag traffic),
// packed-f32 distance math + quarter-rate v_sqrt, then ONE transposing
// butterfly per full row (no LDS, no barriers) -> lanes 0..7 store the
// 8 query scores for this entity.
//
// Occupancy: ~210 VGPR -> 2 waves/SIMD (8 waves/CU); 512 blocks = 2048
// waves co-resident, grid-stride ~15 entities each; next row prefetched
// under ~950 cycles of compute.
// ---------------------------------------------------------------------------
__global__ __launch_bounds__(256, 2) void rotate_score_kernel(
    const float* __restrict__ eemb,
    const float* __restrict__ ws,
    float* __restrict__ out,
    int N)
{
    const int lane  = threadIdx.x & 63;
    const int wid   = threadIdx.x >> 6;
    const int gwave = blockIdx.x * 4 + wid;
    const int nwav  = gridDim.x * 4;

    const int o0 = 4 * lane;              // slice 0: dims [o0, o0+4)
    const int o1 = 256 + 4 * lane;        // slice 1: dims [o1, o1+4)

    // ---- query fragments into registers (32x coalesced f32x4) ----
    f32x4 qr0[N_Q], qr1[N_Q], qi0[N_Q], qi1[N_Q];
    #pragma unroll
    for (int b = 0; b < N_Q; ++b) {
        const float* re = ws + (b << 9);
        const float* im = re + N_Q * EMB_DIM;
        qr0[b] = *(const f32x4*)(re + o0);
        qr1[b] = *(const f32x4*)(re + o1);
        qi0[b] = *(const f32x4*)(im + o0);
        qi1[b] = *(const f32x4*)(im + o1);
    }

    int e = gwave;                        // 2048 waves << N: always valid
    const float* rp = eemb + (size_t)e * (2 * EMB_DIM);
    f32x4 er0 = *(const f32x4*)(rp + o0);
    f32x4 er1 = *(const f32x4*)(rp + o1);
    f32x4 ei0 = *(const f32x4*)(rp + EMB_DIM + o0);
    f32x4 ei1 = *(const f32x4*)(rp + EMB_DIM + o1);

    for (; e < N; e += nwav) {
        // prefetch next entity row (hidden under this row's compute)
        int en = e + nwav;
        int ec = (en < N) ? en : 0;
        const float* np = eemb + (size_t)ec * (2 * EMB_DIM);
        f32x4 nr0 = *(const f32x4*)(np + o0);
        f32x4 nr1 = *(const f32x4*)(np + o1);
        f32x4 ni0 = *(const f32x4*)(np + EMB_DIM + o0);
        f32x4 ni1 = *(const f32x4*)(np + EMB_DIM + o1);

        // ---- distance fragments for all 8 queries ----
        float s[N_Q];
        #pragma unroll
        for (int b = 0; b < N_Q; ++b) {
            f32x4 dx = qr0[b] - er0;
            f32x4 dy = qi0[b] - ei0;
            f32x4 d2 = dx * dx + dy * dy;          // pk_mul + pk_fma
            f32x4 ra;
            ra.x = __builtin_amdgcn_sqrtf(d2.x);
            ra.y = __builtin_amdgcn_sqrtf(d2.y);
            ra.z = __builtin_amdgcn_sqrtf(d2.z);
            ra.w = __builtin_amdgcn_sqrtf(d2.w);
            dx = qr1[b] - er1;
            dy = qi1[b] - ei1;
            d2 = dx * dx + dy * dy;
            f32x4 rb;
            rb.x = __builtin_amdgcn_sqrtf(d2.x);
            rb.y = __builtin_amdgcn_sqrtf(d2.y);
            rb.z = __builtin_amdgcn_sqrtf(d2.z);
            rb.w = __builtin_amdgcn_sqrtf(d2.w);
            f32x4 a = ra + rb;
            s[b] = (a.x + a.y) + (a.z + a.w);
        }

        // ---- transposing butterfly (verified in the 184.8us kernel):
        // lanes 0..7 end with total sums for queries 0..7.
        const bool p1 = lane & 1;
        float u0, u1, u2, u3;
        {
            float x, z;
            x = p1 ? s[1] : s[0]; z = p1 ? s[0] : s[1]; u0 = x + __shfl_xor(z, 1);
            x = p1 ? s[3] : s[2]; z = p1 ? s[2] : s[3]; u1 = x + __shfl_xor(z, 1);
            x = p1 ? s[5] : s[4]; z = p1 ? s[4] : s[5]; u2 = x + __shfl_xor(z, 1);
            x = p1 ? s[7] : s[6]; z = p1 ? s[6] : s[7]; u3 = x + __shfl_xor(z, 1);
        }
        const bool p2 = lane & 2;
        float t0, t1;
        {
            float x, z;
            x = p2 ? u1 : u0; z = p2 ? u0 : u1; t0 = x + __shfl_xor(z, 2);
            x = p2 ? u3 : u2; z = p2 ? u2 : u3; t1 = x + __shfl_xor(z, 2);
        }
        const bool p3 = lane & 4;
        float u;
        {
            float x, z;
            x = p3 ? t1 : t0; z = p3 ? t0 : t1; u = x + __shfl_xor(z, 4);
        }
        u += __shfl_xor(u, 8);
        u += __shfl_xor(u, 16);
        u += __shfl_xor(u, 32);

        if (lane < N_Q) out[(size_t)lane * N + e] = GAMMA_F - u;

        er0 = nr0; er1 = nr1; ei0 = ni0; ei1 = ni1;
    }
}

extern "C" void kernel_launch(void* const* d_in, const int* in_sizes, int n_in,
                              void* d_out, int out_size, void* d_ws, size_t ws_size,
                              hipStream_t stream) {
    const int*   all_h = (const int*)d_in[0];
    const int*   all_r = (const int*)d_in[1];
    const float* eemb  = (const float*)d_in[2];
    const float* remb  = (const float*)d_in[3];
    float* out = (float*)d_out;
    float* ws  = (float*)d_ws;        // needs 2*8*512*4 = 32 KB

    int N = in_sizes[2] / (2 * EMB_DIM);   // 30000

    rotate_queries_kernel<<<16, 256, 0, stream>>>(all_h, all_r, eemb, remb, ws);

    // 512 blocks x 4 waves = 2048 waves, 8/CU at ~210 VGPR: fully co-resident.
    rotate_score_kernel<<<512, 256, 0, stream>>>(eemb, ws, out, N);
}